// Round 1
// baseline (106.968 us; speedup 1.0000x reference)
//
#include <hip/hip_runtime.h>
#include <hip/hip_bf16.h>

// Problem constants
#define BATCH   2
#define NSEQ    4096
#define EDIM    256
#define NHEAD   8
#define HDIM    32
#define TAU     32
#define SCALING 0.17677669529663687f   // HD^-0.5

typedef __attribute__((ext_vector_type(8))) short short8;   // 8 bf16 (4 VGPRs)
typedef __attribute__((ext_vector_type(4))) float floatx4;  // MFMA C/D

__device__ __forceinline__ short f2bf(float f) {
    union { float f; unsigned u; } v; v.f = f;
    unsigned u = v.u;
    unsigned r = (u + 0x7FFFu + ((u >> 16) & 1u)) >> 16;  // RTNE
    return (short)r;
}

// ---------------------------------------------------------------------------
// Kernel 1: P[r, e] = X[r, :] . W[e, :] + b[e]   (X = query|key|value stacked)
// M=24576, N=256, K=256.  128x128 tile, BK=32, 4 waves in 2x2, bf16 MFMA.
// ---------------------------------------------------------------------------
__global__ __launch_bounds__(256) void proj_kernel(
    const float* __restrict__ q, const float* __restrict__ k,
    const float* __restrict__ v, const float* __restrict__ W,
    const float* __restrict__ bias, float* __restrict__ P)
{
    __shared__ short As[128][40];   // X tile  [m][k], pad 32->40 (stride 80B)
    __shared__ short Bs[128][40];   // W tile  [e][k]

    const int tid  = threadIdx.x;
    const int e0   = blockIdx.x * 128;   // 0 or 128
    const int row0 = blockIdx.y * 128;   // 0..24448, 8192%128==0 -> single src
    const int seg  = row0 >> 13;
    const float* X = (seg == 0) ? q : (seg == 1) ? k : v;
    const int xrow0 = row0 & 8191;

    const int lane = tid & 63;
    const int wid  = tid >> 6;
    const int wm   = wid & 1, wn = wid >> 1;
    const int quad = lane >> 4, l16 = lane & 15;

    floatx4 acc[4][4];
    #pragma unroll
    for (int i = 0; i < 4; i++)
        #pragma unroll
        for (int j = 0; j < 4; j++) acc[i][j] = (floatx4)0.0f;

    for (int k0 = 0; k0 < 256; k0 += 32) {
        // Stage A and B tiles: 128 rows x 32 cols fp32 -> bf16 each
        #pragma unroll
        for (int i = 0; i < 4; i++) {
            int idx = tid + i * 256;         // 0..1023
            int row = idx >> 3;              // 0..127
            int c4  = (idx & 7) * 4;         // 0..28
            float4 xa = *(const float4*)(X + (size_t)(xrow0 + row) * 256 + k0 + c4);
            short a0 = f2bf(xa.x), a1 = f2bf(xa.y), a2 = f2bf(xa.z), a3 = f2bf(xa.w);
            As[row][c4 + 0] = a0; As[row][c4 + 1] = a1;
            As[row][c4 + 2] = a2; As[row][c4 + 3] = a3;
            float4 wb = *(const float4*)(W + (size_t)(e0 + row) * 256 + k0 + c4);
            short b0 = f2bf(wb.x), b1 = f2bf(wb.y), b2 = f2bf(wb.z), b3 = f2bf(wb.w);
            Bs[row][c4 + 0] = b0; Bs[row][c4 + 1] = b1;
            Bs[row][c4 + 2] = b2; Bs[row][c4 + 3] = b3;
        }
        __syncthreads();

        short8 a_frag[4], b_frag[4];
        #pragma unroll
        for (int mt = 0; mt < 4; mt++)
            a_frag[mt] = *(const short8*)&As[wm * 64 + mt * 16 + l16][quad * 8];
        #pragma unroll
        for (int nt = 0; nt < 4; nt++)
            b_frag[nt] = *(const short8*)&Bs[wn * 64 + nt * 16 + l16][quad * 8];
        #pragma unroll
        for (int mt = 0; mt < 4; mt++)
            #pragma unroll
            for (int nt = 0; nt < 4; nt++)
                acc[mt][nt] = __builtin_amdgcn_mfma_f32_16x16x32_bf16(
                    a_frag[mt], b_frag[nt], acc[mt][nt], 0, 0, 0);
        __syncthreads();
    }

    // Epilogue: add bias, store fp32.  C/D: col=lane&15, row=quad*4+reg
    #pragma unroll
    for (int nt = 0; nt < 4; nt++) {
        int col = e0 + wn * 64 + nt * 16 + l16;
        float bv = bias[col];
        #pragma unroll
        for (int mt = 0; mt < 4; mt++) {
            int rbase = row0 + wm * 64 + mt * 16 + quad * 4;
            #pragma unroll
            for (int r = 0; r < 4; r++)
                P[(size_t)(rbase + r) * 256 + col] = acc[mt][nt][r] + bv;
        }
    }
}

// ---------------------------------------------------------------------------
// Kernel 2: sliding-window attention.  Block = (b, n-tile of 64, head-pair).
// Thread owns one (n, h).  K/V tiles (95 rows halo) staged in LDS fp32.
// Padded positions (j<0) project to the bias vector.
// ---------------------------------------------------------------------------
__global__ __launch_bounds__(128) void attn_kernel(
    const float* __restrict__ P, const float* __restrict__ bias,
    float* __restrict__ out)
{
    __shared__ float Ks[95][68];   // stride 68 floats = 272B (16B-aligned rows)
    __shared__ float Vs[95][68];

    const int tid = threadIdx.x;
    const int n0  = blockIdx.x * 64;
    const int hp  = blockIdx.y;        // head pair 0..3
    const int b   = blockIdx.z;
    const int cb  = hp * 64;           // col base within E

    const float* Kp = P + (size_t)8192 * 256;
    const float* Vp = P + (size_t)16384 * 256;

    // Stage K/V rows [n0-31, n0+64) x 64 cols
    for (int idx = tid; idx < 95 * 16; idx += 128) {
        int row = idx >> 4;
        int c4  = (idx & 15) * 4;
        int j   = n0 - 31 + row;
        float4 kv, vv;
        if (j >= 0) {
            size_t g = (size_t)(b * 4096 + j) * 256 + cb + c4;
            kv = *(const float4*)(Kp + g);
            vv = *(const float4*)(Vp + g);
        } else {
            kv = *(const float4*)(bias + cb + c4);  // proj(0) = bias
            vv = kv;
        }
        *(float4*)&Ks[row][c4] = kv;
        *(float4*)&Vs[row][c4] = vv;
    }
    __syncthreads();

    const int hl = tid >> 6;    // 0..1 within pair
    const int nl = tid & 63;
    const int n  = n0 + nl;
    const int cl = hl * 32;

    // q for this (n, h)
    float4 qr[8];
    const float* qp = P + (size_t)(b * 4096 + n) * 256 + cb + cl;
    #pragma unroll
    for (int dc = 0; dc < 8; dc++) qr[dc] = *(const float4*)(qp + dc * 4);

    // Scores over window t=0..31 (key index j = n + t - 31 -> LDS row nl + t)
    float s[32];
    #pragma unroll
    for (int t = 0; t < 32; t++) {
        float acc = 0.f;
        #pragma unroll
        for (int dc = 0; dc < 8; dc++) {
            float4 kk = *(const float4*)&Ks[nl + t][cl + dc * 4];
            acc += qr[dc].x * kk.x + qr[dc].y * kk.y +
                   qr[dc].z * kk.z + qr[dc].w * kk.w;
        }
        s[t] = acc * SCALING;
    }

    float m = s[0];
    #pragma unroll
    for (int t = 1; t < 32; t++) m = fmaxf(m, s[t]);
    float l = 0.f;
    #pragma unroll
    for (int t = 0; t < 32; t++) { s[t] = __expf(s[t] - m); l += s[t]; }
    float inv = 1.0f / l;

    float4 o[8];
    #pragma unroll
    for (int dc = 0; dc < 8; dc++) o[dc] = make_float4(0.f, 0.f, 0.f, 0.f);
    #pragma unroll
    for (int t = 0; t < 32; t++) {
        float a = s[t] * inv;
        #pragma unroll
        for (int dc = 0; dc < 8; dc++) {
            float4 vv = *(const float4*)&Vs[nl + t][cl + dc * 4];
            o[dc].x += a * vv.x; o[dc].y += a * vv.y;
            o[dc].z += a * vv.z; o[dc].w += a * vv.w;
        }
    }

    float* op = out + (size_t)(b * 4096 + n) * 256 + cb + cl;
    #pragma unroll
    for (int dc = 0; dc < 8; dc++) *(float4*)(op + dc * 4) = o[dc];
}

extern "C" void kernel_launch(void* const* d_in, const int* in_sizes, int n_in,
                              void* d_out, int out_size, void* d_ws, size_t ws_size,
                              hipStream_t stream) {
    (void)in_sizes; (void)n_in; (void)out_size; (void)ws_size;
    const float* q    = (const float*)d_in[0];
    const float* k    = (const float*)d_in[1];
    const float* v    = (const float*)d_in[2];
    const float* W    = (const float*)d_in[3];
    const float* bias = (const float*)d_in[4];
    float* P   = (float*)d_ws;   // 24576 x 256 fp32 = 24 MB: Qp | Kp | Vp
    float* out = (float*)d_out;

    dim3 g1(2, 192), b1(256);
    hipLaunchKernelGGL(proj_kernel, g1, b1, 0, stream, q, k, v, W, bias, P);
    dim3 g2(64, 4, 2), b2(128);
    hipLaunchKernelGGL(attn_kernel, g2, b2, 0, stream, P, bias, out);
}

// Round 3
// 102.732 us; speedup vs baseline: 1.0412x; 1.0412x over previous
//
#include <hip/hip_runtime.h>
#include <hip/hip_bf16.h>

#define SCALING 0.17677669529663687f   // HD^-0.5

typedef __attribute__((ext_vector_type(8))) short bf8;     // 8 bf16, 16 B
typedef __attribute__((ext_vector_type(4))) short bf4;     // 4 bf16, 8 B
typedef __attribute__((ext_vector_type(4))) float floatx4; // MFMA C/D

__device__ __forceinline__ short f2bf(float f) {
    union { float f; unsigned u; } v; v.f = f;
    unsigned u = v.u;
    return (short)((u + 0x7FFFu + ((u >> 16) & 1u)) >> 16);  // RTNE
}
__device__ __forceinline__ float bf2f(short s) {
    union { unsigned u; float f; } v;
    v.u = ((unsigned)(unsigned short)s) << 16;
    return v.f;
}

// ---------------------------------------------------------------------------
// Kernel 0: W fp32 -> bf16  (65536 elems; 64 blocks x 256 thr x 4)
// ---------------------------------------------------------------------------
__global__ __launch_bounds__(256) void wconv_kernel(
    const float* __restrict__ W, short* __restrict__ Wbf)
{
    int idx = (blockIdx.x * 256 + threadIdx.x) * 4;
    float4 w = *(const float4*)(W + idx);
    bf4 p;
    p[0] = f2bf(w.x); p[1] = f2bf(w.y); p[2] = f2bf(w.z); p[3] = f2bf(w.w);
    *(bf4*)(Wbf + idx) = p;
}

// ---------------------------------------------------------------------------
// Kernel 1: P = X @ W^T + b,  X = q|k|v stacked (24576 x 256), K=256.
// Tile 64 rows x 256 cols, 512 threads (8 waves, 2m x 4n, wave-tile 32x64).
// Output P in bf16 "row-quad" layout: P[(row>>2)*1024 + col*4 + (row&3)].
// ---------------------------------------------------------------------------
__global__ __launch_bounds__(512) void proj_kernel(
    const float* __restrict__ q, const float* __restrict__ k,
    const float* __restrict__ v, const short* __restrict__ Wbf,
    const float* __restrict__ bias, short* __restrict__ Pbf)
{
    __shared__ short As[64][40];    // X tile  [m][k], pad 32->40
    __shared__ short Bs[256][40];   // W tile  [e][k]

    const int tid  = threadIdx.x;
    const int row0 = blockIdx.x * 64;            // 0..24512
    const int seg  = row0 >> 13;
    const float* X = (seg == 0) ? q : (seg == 1) ? k : v;
    const int xrow0 = row0 & 8191;

    const int lane = tid & 63;
    const int wid  = tid >> 6;       // 0..7
    const int wm   = wid & 1, wn = wid >> 1;     // 2 x 4 wave grid
    const int quad = lane >> 4, l16 = lane & 15;

    // staging coords
    const int arow = tid >> 3;             // 0..63
    const int ac4  = (tid & 7) * 4;        // 0..28
    const int brow = tid >> 1;             // 0..255
    const int bh   = (tid & 1) * 16;       // 0 or 16 (16 cols per thread)

    floatx4 acc[2][4];
    #pragma unroll
    for (int i = 0; i < 2; i++)
        #pragma unroll
        for (int j = 0; j < 4; j++) acc[i][j] = (floatx4)0.0f;

    for (int k0 = 0; k0 < 256; k0 += 32) {
        // A: 64x32 fp32 -> bf16 (4 elems/thread, one packed 8B write)
        float4 xa = *(const float4*)(X + (size_t)(xrow0 + arow) * 256 + k0 + ac4);
        bf4 ap;
        ap[0] = f2bf(xa.x); ap[1] = f2bf(xa.y);
        ap[2] = f2bf(xa.z); ap[3] = f2bf(xa.w);
        // B: 256x32 bf16 pure copy — 16 shorts/thread (two b128): full coverage
        bf8 wb0 = *(const bf8*)(Wbf + brow * 256 + k0 + bh);
        bf8 wb1 = *(const bf8*)(Wbf + brow * 256 + k0 + bh + 8);
        __syncthreads();               // protect LDS from previous iter reads
        *(bf4*)&As[arow][ac4]     = ap;
        *(bf8*)&Bs[brow][bh]      = wb0;
        *(bf8*)&Bs[brow][bh + 8]  = wb1;
        __syncthreads();

        bf8 a_frag[2], b_frag[4];
        #pragma unroll
        for (int mt = 0; mt < 2; mt++)
            a_frag[mt] = *(const bf8*)&As[wm * 32 + mt * 16 + l16][quad * 8];
        #pragma unroll
        for (int nt = 0; nt < 4; nt++)
            b_frag[nt] = *(const bf8*)&Bs[wn * 64 + nt * 16 + l16][quad * 8];
        #pragma unroll
        for (int mt = 0; mt < 2; mt++)
            #pragma unroll
            for (int nt = 0; nt < 4; nt++)
                acc[mt][nt] = __builtin_amdgcn_mfma_f32_16x16x32_bf16(
                    a_frag[mt], b_frag[nt], acc[mt][nt], 0, 0, 0);
    }

    // Epilogue: +bias, bf16 row-quad layout, contiguous 8B stores per lane.
    #pragma unroll
    for (int nt = 0; nt < 4; nt++) {
        int col = wn * 64 + nt * 16 + l16;
        float bv = bias[col];
        #pragma unroll
        for (int mt = 0; mt < 2; mt++) {
            int rbase = row0 + wm * 32 + mt * 16 + quad * 4;
            bf4 pk;
            #pragma unroll
            for (int r = 0; r < 4; r++) pk[r] = f2bf(acc[mt][nt][r] + bv);
            *(bf4*)(Pbf + (size_t)(rbase >> 2) * 1024 + col * 4) = pk;
        }
    }
}

// ---------------------------------------------------------------------------
// Kernel 2: sliding-window attention.  Block = (n-tile 64, head-pair, b).
// Stage Q (64 rows) and K/V (96 rows incl. halo) x 64 cols from quad-P,
// unpack bf16->fp32 into LDS (stride 68: bank-minimal b128 reads).
// ---------------------------------------------------------------------------
__global__ __launch_bounds__(128) void attn_kernel(
    const short* __restrict__ Pbf, const float* __restrict__ bias,
    float* __restrict__ out)
{
    __shared__ float Qs[64][68];
    __shared__ float Ks[96][68];
    __shared__ float Vs[96][68];

    const int tid = threadIdx.x;
    const int n0  = blockIdx.x * 64;
    const int hp  = blockIdx.y;
    const int b   = blockIdx.z;
    const int cb  = hp * 64;
    const int qquad0 = (b * 4096 + n0) >> 2;
    const int kquad  = (8192  + b * 4096) >> 2;
    const int vquad  = (16384 + b * 4096) >> 2;

    // --- K/V staging: 24 quads x 32 col-pairs each, rows jbase..jbase+95 ---
    const int jbase = n0 - 32;
    for (int i = 0; i < 12; i++) {
        int idx  = tid + i * 128;          // 0..1535
        int isV  = idx >= 768;
        int r    = idx - (isV ? 768 : 0);  // 0..767
        int qd   = r >> 5;                 // 0..23
        int u    = r & 31;                 // col pair
        int c    = u * 2;
        int jq   = jbase + qd * 4;         // first global j of this quad
        float c0v[4], c1v[4];
        if (jq >= 0) {
            int quad = (isV ? vquad : kquad) + (jq >> 2);
            bf8 s = *(const bf8*)(Pbf + (size_t)quad * 1024 + (cb + c) * 4);
            #pragma unroll
            for (int rr = 0; rr < 4; rr++) { c0v[rr] = bf2f(s[rr]); c1v[rr] = bf2f(s[4 + rr]); }
        } else {
            float b0 = bias[cb + c], b1 = bias[cb + c + 1];
            #pragma unroll
            for (int rr = 0; rr < 4; rr++) { c0v[rr] = b0; c1v[rr] = b1; }
        }
        float (*T)[68] = isV ? Vs : Ks;
        #pragma unroll
        for (int rr = 0; rr < 4; rr++) {
            float2 w2 = make_float2(c0v[rr], c1v[rr]);
            *(float2*)&T[qd * 4 + rr][c] = w2;
        }
    }
    // --- Q staging: 16 quads x 32 col-pairs ---
    for (int i = 0; i < 4; i++) {
        int idx = tid + i * 128;           // 0..511
        int qd  = idx >> 5;                // 0..15
        int u   = idx & 31;
        int c   = u * 2;
        bf8 s = *(const bf8*)(Pbf + (size_t)(qquad0 + qd) * 1024 + (cb + c) * 4);
        #pragma unroll
        for (int rr = 0; rr < 4; rr++) {
            float2 w2 = make_float2(bf2f(s[rr]), bf2f(s[4 + rr]));
            *(float2*)&Qs[qd * 4 + rr][c] = w2;
        }
    }
    __syncthreads();

    const int hl = tid >> 6;    // head within pair
    const int nl = tid & 63;
    const int n  = n0 + nl;
    const int cl = hl * 32;

    float4 qr[8];
    #pragma unroll
    for (int dc = 0; dc < 8; dc++) qr[dc] = *(const float4*)&Qs[nl][cl + dc * 4];

    float s[32];
    #pragma unroll
    for (int t = 0; t < 32; t++) {
        float acc = 0.f;
        int ri = nl + 1 + t;   // global j = n0+nl-31+t
        #pragma unroll
        for (int dc = 0; dc < 8; dc++) {
            float4 kk = *(const float4*)&Ks[ri][cl + dc * 4];
            acc += qr[dc].x * kk.x + qr[dc].y * kk.y +
                   qr[dc].z * kk.z + qr[dc].w * kk.w;
        }
        s[t] = acc * SCALING;
    }

    float m = s[0];
    #pragma unroll
    for (int t = 1; t < 32; t++) m = fmaxf(m, s[t]);
    float l = 0.f;
    #pragma unroll
    for (int t = 0; t < 32; t++) { s[t] = __expf(s[t] - m); l += s[t]; }
    float inv = 1.0f / l;

    float4 o[8];
    #pragma unroll
    for (int dc = 0; dc < 8; dc++) o[dc] = make_float4(0.f, 0.f, 0.f, 0.f);
    #pragma unroll
    for (int t = 0; t < 32; t++) {
        float a = s[t] * inv;
        int ri = nl + 1 + t;
        #pragma unroll
        for (int dc = 0; dc < 8; dc++) {
            float4 vv = *(const float4*)&Vs[ri][cl + dc * 4];
            o[dc].x += a * vv.x; o[dc].y += a * vv.y;
            o[dc].z += a * vv.z; o[dc].w += a * vv.w;
        }
    }

    float* op = out + (size_t)(b * 4096 + n) * 256 + cb + cl;
    #pragma unroll
    for (int dc = 0; dc < 8; dc++) *(float4*)(op + dc * 4) = o[dc];
}

extern "C" void kernel_launch(void* const* d_in, const int* in_sizes, int n_in,
                              void* d_out, int out_size, void* d_ws, size_t ws_size,
                              hipStream_t stream) {
    (void)in_sizes; (void)n_in; (void)out_size; (void)ws_size;
    const float* q    = (const float*)d_in[0];
    const float* k    = (const float*)d_in[1];
    const float* v    = (const float*)d_in[2];
    const float* W    = (const float*)d_in[3];
    const float* bias = (const float*)d_in[4];

    short* Wbf = (short*)d_ws;                       // 128 KB
    short* Pbf = (short*)d_ws + 524288;              // 1 MB offset; 12.6 MB quad-P
    float* outp = (float*)d_out;

    hipLaunchKernelGGL(wconv_kernel, dim3(64), dim3(256), 0, stream, W, Wbf);
    hipLaunchKernelGGL(proj_kernel, dim3(384), dim3(512), 0, stream,
                       q, k, v, Wbf, bias, Pbf);
    hipLaunchKernelGGL(attn_kernel, dim3(64, 4, 2), dim3(128), 0, stream,
                       Pbf, bias, outp);
}

// Round 4
// 97.140 us; speedup vs baseline: 1.1012x; 1.0576x over previous
//
#include <hip/hip_runtime.h>

#define SCALING 0.17677669529663687f   // HD^-0.5

typedef __attribute__((ext_vector_type(8))) short bf8;     // 8 bf16, 16 B
typedef __attribute__((ext_vector_type(4))) short bf4;     // 4 bf16, 8 B
typedef __attribute__((ext_vector_type(4))) float floatx4; // MFMA C/D

__device__ __forceinline__ short f2bf(float f) {
    union { float f; unsigned u; } v; v.f = f;
    unsigned u = v.u;
    return (short)((u + 0x7FFFu + ((u >> 16) & 1u)) >> 16);  // RTNE
}
__device__ __forceinline__ float bf2f(short s) {
    union { unsigned u; float f; } v;
    v.u = ((unsigned)(unsigned short)s) << 16;
    return v.f;
}

#define PSTR 264   // P-LDS row stride (shorts): 132 dwords == 4 mod 32 -> minimal conflicts
#define MSTR 36    // merge row stride (floats): 16B-aligned rows, == 4 mod 32

// ---------------------------------------------------------------------------
// ONE fused kernel.  Block = (n-tile of 32, batch).  512 threads, 1 block/CU.
// Phase 1: project rows [Q(32) | K(64: j=n0-32..n0+31) | V(64)] x 256 cols
//          with bf16 MFMA (M=160,N=256,K=256, BK=32), P stays in LDS (bf16).
//          Rows with j<0 use zero input -> projection == bias (matches ref pad).
// Phase 2: windowed attention; thread pair (t in [0,16) / [16,32)) per (n,h),
//          online-softmax merge through LDS; coalesced float4 output store.
// ---------------------------------------------------------------------------
__global__ __launch_bounds__(512, 2) void fused_kernel(
    const float* __restrict__ q, const float* __restrict__ k,
    const float* __restrict__ v, const float* __restrict__ W,
    const float* __restrict__ bias, float* __restrict__ out)
{
    __shared__ short Pl[160][PSTR];   // 84480 B projected Q|K|V (bf16)
    __shared__ short As[160][40];     // X staging tile  [m][k]
    __shared__ short Bs[256][40];     // W staging tile  [e][k]
    __shared__ float Mg[256][MSTR];   // merge buffer: o[32], m, l

    const int tid = threadIdx.x;
    const int n0  = blockIdx.x * 32;
    const int b   = blockIdx.y;
    const int lane = tid & 63, wid = tid >> 6;
    const int wm = wid & 1, wn = wid >> 1;       // 2m x 4n wave grid
    const int quad = lane >> 4, l16 = lane & 15;

    // ---- Phase 1: precompute staging coords (fixed across k-steps) ----
    // A rows: r<32 -> q row n0+r; 32<=r<96 -> k row j=n0+r-64; 96<=r<160 -> v row j=n0+r-128
    int a_row[3]; int a_c4[3]; const float* a_ptr[3];
    #pragma unroll
    for (int i = 0; i < 3; i++) {
        int idx = tid + i * 512;
        if (idx < 1280) {
            int r = idx >> 3;
            a_row[i] = r;
            a_c4[i]  = (idx & 7) * 4;
            const float* p;
            if (r < 32) {
                p = q + (size_t)(b * 4096 + n0 + r) * 256;
            } else if (r < 96) {
                int j = n0 + r - 64;
                p = (j >= 0) ? (k + (size_t)(b * 4096 + j) * 256) : nullptr;
            } else {
                int j = n0 + r - 128;
                p = (j >= 0) ? (v + (size_t)(b * 4096 + j) * 256) : nullptr;
            }
            a_ptr[i] = p;
        } else { a_row[i] = -1; a_c4[i] = 0; a_ptr[i] = nullptr; }
    }
    int w_row[4], w_c4[4];
    #pragma unroll
    for (int i = 0; i < 4; i++) {
        int idx = tid + i * 512;       // < 2048 always
        w_row[i] = idx >> 3;
        w_c4[i]  = (idx & 7) * 4;
    }

    floatx4 acc[5][4];
    #pragma unroll
    for (int mt = 0; mt < 5; mt++)
        #pragma unroll
        for (int nt = 0; nt < 4; nt++) acc[mt][nt] = (floatx4)0.0f;

    for (int k0 = 0; k0 < 256; k0 += 32) {
        // global loads + fp32->bf16 convert (registers)
        bf4 ab[3];
        #pragma unroll
        for (int i = 0; i < 3; i++) {
            float4 xa = make_float4(0.f, 0.f, 0.f, 0.f);
            if (a_ptr[i]) xa = *(const float4*)(a_ptr[i] + k0 + a_c4[i]);
            ab[i][0] = f2bf(xa.x); ab[i][1] = f2bf(xa.y);
            ab[i][2] = f2bf(xa.z); ab[i][3] = f2bf(xa.w);
        }
        bf4 wb[4];
        #pragma unroll
        for (int i = 0; i < 4; i++) {
            float4 wv = *(const float4*)(W + (size_t)w_row[i] * 256 + k0 + w_c4[i]);
            wb[i][0] = f2bf(wv.x); wb[i][1] = f2bf(wv.y);
            wb[i][2] = f2bf(wv.z); wb[i][3] = f2bf(wv.w);
        }
        __syncthreads();   // prior iter's frag reads done
        #pragma unroll
        for (int i = 0; i < 3; i++)
            if (a_row[i] >= 0) *(bf4*)&As[a_row[i]][a_c4[i]] = ab[i];
        #pragma unroll
        for (int i = 0; i < 4; i++)
            *(bf4*)&Bs[w_row[i]][w_c4[i]] = wb[i];
        __syncthreads();

        bf8 af[5], bfr[4];
        #pragma unroll
        for (int mt = 0; mt < 5; mt++)
            af[mt] = *(const bf8*)&As[wm * 80 + mt * 16 + l16][quad * 8];
        #pragma unroll
        for (int nt = 0; nt < 4; nt++)
            bfr[nt] = *(const bf8*)&Bs[wn * 64 + nt * 16 + l16][quad * 8];
        #pragma unroll
        for (int mt = 0; mt < 5; mt++)
            #pragma unroll
            for (int nt = 0; nt < 4; nt++)
                acc[mt][nt] = __builtin_amdgcn_mfma_f32_16x16x32_bf16(
                    af[mt], bfr[nt], acc[mt][nt], 0, 0, 0);
    }

    // Epilogue: +bias, write P to LDS (bf16). C/D: col=l16, row=quad*4+r
    #pragma unroll
    for (int nt = 0; nt < 4; nt++) {
        int col = wn * 64 + nt * 16 + l16;
        float bv = bias[col];
        #pragma unroll
        for (int mt = 0; mt < 5; mt++) {
            int rb = wm * 80 + mt * 16 + quad * 4;
            #pragma unroll
            for (int r = 0; r < 4; r++)
                Pl[rb + r][col] = f2bf(acc[mt][nt][r] + bv);
        }
    }
    __syncthreads();

    // ---- Phase 2: windowed attention ----
    const int pid  = tid & 255;        // (n,h) pair
    const int half = tid >> 8;         // t-window half
    const int nl   = pid & 31;
    const int h    = pid >> 5;
    const int cb   = h * 32;
    const int t0   = half * 16;

    float qv[32];
    #pragma unroll
    for (int c = 0; c < 4; c++) {
        bf8 t = *(const bf8*)&Pl[nl][cb + c * 8];
        #pragma unroll
        for (int e = 0; e < 8; e++) qv[c * 8 + e] = bf2f(t[e]);
    }

    float s[16], m = -3.0e38f;
    #pragma unroll
    for (int tt = 0; tt < 16; tt++) {
        int r = 33 + nl + t0 + tt;     // K row for j = n0+nl-31+(t0+tt)
        float a = 0.f;
        #pragma unroll
        for (int c = 0; c < 4; c++) {
            bf8 kk = *(const bf8*)&Pl[r][cb + c * 8];
            #pragma unroll
            for (int e = 0; e < 8; e++) a += qv[c * 8 + e] * bf2f(kk[e]);
        }
        s[tt] = a * SCALING;
        m = fmaxf(m, s[tt]);
    }
    float l = 0.f;
    #pragma unroll
    for (int tt = 0; tt < 16; tt++) { s[tt] = __expf(s[tt] - m); l += s[tt]; }

    float o[32];
    #pragma unroll
    for (int e = 0; e < 32; e++) o[e] = 0.f;
    #pragma unroll
    for (int tt = 0; tt < 16; tt++) {
        int r = 97 + nl + t0 + tt;     // V row
        float a = s[tt];
        #pragma unroll
        for (int c = 0; c < 4; c++) {
            bf8 vv = *(const bf8*)&Pl[r][cb + c * 8];
            #pragma unroll
            for (int e = 0; e < 8; e++) o[c * 8 + e] += a * bf2f(vv[e]);
        }
    }

    // merge halves (online softmax)
    if (half == 1) {
        #pragma unroll
        for (int c = 0; c < 16; c++)
            *(float2*)&Mg[pid][c * 2] = make_float2(o[c * 2], o[c * 2 + 1]);
        Mg[pid][32] = m; Mg[pid][33] = l;
    }
    __syncthreads();
    if (half == 0) {
        float m1 = Mg[pid][32], l1 = Mg[pid][33];
        float mm = fmaxf(m, m1);
        float a0 = __expf(m - mm), a1 = __expf(m1 - mm);
        float inv = 1.0f / (a0 * l + a1 * l1);
        #pragma unroll
        for (int c = 0; c < 16; c++) {
            float2 o1 = *(const float2*)&Mg[pid][c * 2];
            float2 r2 = make_float2((a0 * o[c * 2]     + a1 * o1.x) * inv,
                                    (a0 * o[c * 2 + 1] + a1 * o1.y) * inv);
            *(float2*)&Mg[pid][c * 2] = r2;
        }
    }
    __syncthreads();

    // coalesced store: 32 rows x 256 cols
    const size_t obase = ((size_t)b * 4096 + n0) * 256;
    #pragma unroll
    for (int i = 0; i < 4; i++) {
        int t4   = tid + i * 512;      // 0..2047 float4 slots
        int e    = t4 * 4;
        int n    = e >> 8;
        int rest = e & 255;
        int hh   = rest >> 5, cc = rest & 31;
        int pp   = hh * 32 + n;
        float4 val = *(const float4*)&Mg[pp][cc];
        *(float4*)(out + obase + (size_t)n * 256 + rest) = val;
    }
}

extern "C" void kernel_launch(void* const* d_in, const int* in_sizes, int n_in,
                              void* d_out, int out_size, void* d_ws, size_t ws_size,
                              hipStream_t stream) {
    (void)in_sizes; (void)n_in; (void)out_size; (void)d_ws; (void)ws_size;
    const float* q    = (const float*)d_in[0];
    const float* k    = (const float*)d_in[1];
    const float* v    = (const float*)d_in[2];
    const float* W    = (const float*)d_in[3];
    const float* bias = (const float*)d_in[4];
    float* outp = (float*)d_out;

    hipLaunchKernelGGL(fused_kernel, dim3(128, 2), dim3(512), 0, stream,
                       q, k, v, W, bias, outp);
}

// Round 5
// 91.680 us; speedup vs baseline: 1.1668x; 1.0596x over previous
//
#include <hip/hip_runtime.h>

#define SCALING 0.17677669529663687f   // HD^-0.5

typedef __attribute__((ext_vector_type(8))) short bf8;      // 8 bf16
typedef __attribute__((ext_vector_type(4))) short bf4;      // 4 bf16
typedef _Float16 half8 __attribute__((ext_vector_type(8))); // 8 f16
typedef _Float16 half4 __attribute__((ext_vector_type(4))); // 4 f16
typedef __attribute__((ext_vector_type(4))) float floatx4;  // MFMA C/D

__device__ __forceinline__ short f2bf(float f) {
    union { float f; unsigned u; } v; v.f = f;
    unsigned u = v.u;
    return (short)((u + 0x7FFFu + ((u >> 16) & 1u)) >> 16);  // RTNE
}

#define PSTR 264   // Pl row stride (shorts): 132 dwords == 4 mod 32
#define VSTR 72    // Vt/Ps row stride (halfs): 36 dwords == 4 mod 32

// ---------------------------------------------------------------------------
// ONE fused kernel.  Block = (n-tile of 32, batch).  512 threads, 1 block/CU.
// Phase 1: MFMA-project rows [Q(32,pre-scaled) | K(64: j=n0-32..n0+31) |
//          V(64)] x 256 cols.  Q,K -> Pl (bf16); V -> Vt TRANSPOSED (f16).
//          j<0 rows use zero input -> projection == bias (matches ref pad).
// Phase 2: one head per wave.  S = Q.K^T (6 MFMAs, banded), softmax in
//          C-layout regs (shfl_xor over 16-lane col group), P -> per-wave
//          Ps scratch (f16, C->A relayout), O = P.V via 8 f16 MFMAs,
//          scale by 1/l on C-frags, direct global stores.
// ---------------------------------------------------------------------------
__global__ __launch_bounds__(512, 2) void fused_kernel(
    const float* __restrict__ q, const float* __restrict__ k,
    const float* __restrict__ v, const float* __restrict__ W,
    const float* __restrict__ bias, float* __restrict__ out)
{
    __shared__ short    Pl[96][PSTR];     // 50688 B  projected Q|K (bf16)
    __shared__ _Float16 Vt[256][VSTR];    // 36864 B  projected V, [d][i] (f16)
    __shared__ _Float16 Ps[8][32][VSTR];  // 36864 B  per-wave P scratch (f16)
    __shared__ short    As[160][40];      // 12800 B  X staging
    __shared__ short    Bs[256][40];      // 20480 B  W staging

    const int tid = threadIdx.x;
    const int n0  = blockIdx.x * 32;
    const int b   = blockIdx.y;
    const int lane = tid & 63, wid = tid >> 6;
    const int wm = wid & 1, wn = wid >> 1;       // 2m x 4n wave grid
    const int quad = lane >> 4, l16 = lane & 15;

    // ---- Phase 1 staging coords ----
    // A rows: r<32 -> q row n0+r; 32<=r<96 -> k row j=n0+r-64; 96<=r<160 -> v row j=n0+r-128
    int a_row[3]; int a_c4[3]; const float* a_ptr[3];
    #pragma unroll
    for (int i = 0; i < 3; i++) {
        int idx = tid + i * 512;
        if (idx < 1280) {
            int r = idx >> 3;
            a_row[i] = r;
            a_c4[i]  = (idx & 7) * 4;
            const float* p;
            if (r < 32) {
                p = q + (size_t)(b * 4096 + n0 + r) * 256;
            } else if (r < 96) {
                int j = n0 + r - 64;
                p = (j >= 0) ? (k + (size_t)(b * 4096 + j) * 256) : nullptr;
            } else {
                int j = n0 + r - 128;
                p = (j >= 0) ? (v + (size_t)(b * 4096 + j) * 256) : nullptr;
            }
            a_ptr[i] = p;
        } else { a_row[i] = -1; a_c4[i] = 0; a_ptr[i] = nullptr; }
    }
    int w_row[4], w_c4[4];
    #pragma unroll
    for (int i = 0; i < 4; i++) {
        int idx = tid + i * 512;
        w_row[i] = idx >> 3;
        w_c4[i]  = (idx & 7) * 4;
    }

    floatx4 acc[5][4];
    #pragma unroll
    for (int mt = 0; mt < 5; mt++)
        #pragma unroll
        for (int nt = 0; nt < 4; nt++) acc[mt][nt] = (floatx4)0.0f;

    for (int k0 = 0; k0 < 256; k0 += 32) {
        bf4 ab[3];
        #pragma unroll
        for (int i = 0; i < 3; i++) {
            float4 xa = make_float4(0.f, 0.f, 0.f, 0.f);
            if (a_ptr[i]) xa = *(const float4*)(a_ptr[i] + k0 + a_c4[i]);
            ab[i][0] = f2bf(xa.x); ab[i][1] = f2bf(xa.y);
            ab[i][2] = f2bf(xa.z); ab[i][3] = f2bf(xa.w);
        }
        bf4 wb[4];
        #pragma unroll
        for (int i = 0; i < 4; i++) {
            float4 wv = *(const float4*)(W + (size_t)w_row[i] * 256 + k0 + w_c4[i]);
            wb[i][0] = f2bf(wv.x); wb[i][1] = f2bf(wv.y);
            wb[i][2] = f2bf(wv.z); wb[i][3] = f2bf(wv.w);
        }
        __syncthreads();
        #pragma unroll
        for (int i = 0; i < 3; i++)
            if (a_row[i] >= 0) *(bf4*)&As[a_row[i]][a_c4[i]] = ab[i];
        #pragma unroll
        for (int i = 0; i < 4; i++)
            *(bf4*)&Bs[w_row[i]][w_c4[i]] = wb[i];
        __syncthreads();

        bf8 af[5], bfr[4];
        #pragma unroll
        for (int mt = 0; mt < 5; mt++)
            af[mt] = *(const bf8*)&As[wm * 80 + mt * 16 + l16][quad * 8];
        #pragma unroll
        for (int nt = 0; nt < 4; nt++)
            bfr[nt] = *(const bf8*)&Bs[wn * 64 + nt * 16 + l16][quad * 8];
        #pragma unroll
        for (int mt = 0; mt < 5; mt++)
            #pragma unroll
            for (int nt = 0; nt < 4; nt++)
                acc[mt][nt] = __builtin_amdgcn_mfma_f32_16x16x32_bf16(
                    af[mt], bfr[nt], acc[mt][nt], 0, 0, 0);
    }

    // Epilogue: +bias; Q rows pre-scaled by SCALING -> Pl; K -> Pl; V -> Vt^T
    #pragma unroll
    for (int nt = 0; nt < 4; nt++) {
        int col = wn * 64 + nt * 16 + l16;
        float bv = bias[col];
        #pragma unroll
        for (int mt = 0; mt < 5; mt++) {
            int rb = wm * 80 + mt * 16 + quad * 4;   // wave-uniform band per (wm,mt)
            if (rb < 96) {
                const bool isQ = (rb < 32);
                #pragma unroll
                for (int r = 0; r < 4; r++) {
                    float val = acc[mt][nt][r] + bv;
                    Pl[rb + r][col] = f2bf(isQ ? val * SCALING : val);
                }
            } else {
                half4 hv;
                #pragma unroll
                for (int r = 0; r < 4; r++) hv[r] = (_Float16)(acc[mt][nt][r] + bv);
                *(half4*)&Vt[col][rb - 96] = hv;
            }
        }
    }
    __syncthreads();

    // ---- Phase 2: one head per wave ----
    const int h  = wid;
    const int cb = h * 32;

    // S = Q.K^T : A-frags from Q rows, B-frags from K rows (both contiguous-d)
    bf8 qf[2], kf[4];
    #pragma unroll
    for (int mt = 0; mt < 2; mt++)
        qf[mt] = *(const bf8*)&Pl[mt * 16 + l16][cb + quad * 8];
    #pragma unroll
    for (int jt = 0; jt < 4; jt++)
        kf[jt] = *(const bf8*)&Pl[32 + jt * 16 + l16][cb + quad * 8];

    floatx4 S[2][4];
    S[0][0] = __builtin_amdgcn_mfma_f32_16x16x32_bf16(qf[0], kf[0], (floatx4)0.f, 0, 0, 0);
    S[0][1] = __builtin_amdgcn_mfma_f32_16x16x32_bf16(qf[0], kf[1], (floatx4)0.f, 0, 0, 0);
    S[0][2] = __builtin_amdgcn_mfma_f32_16x16x32_bf16(qf[0], kf[2], (floatx4)0.f, 0, 0, 0);
    S[1][1] = __builtin_amdgcn_mfma_f32_16x16x32_bf16(qf[1], kf[1], (floatx4)0.f, 0, 0, 0);
    S[1][2] = __builtin_amdgcn_mfma_f32_16x16x32_bf16(qf[1], kf[2], (floatx4)0.f, 0, 0, 0);
    S[1][3] = __builtin_amdgcn_mfma_f32_16x16x32_bf16(qf[1], kf[3], (floatx4)0.f, 0, 0, 0);

    // Band mask + softmax.  Row n = mt*16+quad*4+r; col i = jt*16+l16;
    // valid iff n+1 <= i <= n+32.  Row stats via shfl_xor over l16 group.
    float p[2][3][4], inv[2][4];
    #pragma unroll
    for (int mt = 0; mt < 2; mt++) {
        #pragma unroll
        for (int r = 0; r < 4; r++) {
            int n = mt * 16 + quad * 4 + r;
            float sv[3], mx = -3.0e38f;
            #pragma unroll
            for (int u = 0; u < 3; u++) {
                int i = (u + mt) * 16 + l16;
                bool valid = (i > n) && (i <= n + 32);
                sv[u] = valid ? S[mt][u + mt][r] : -3.0e38f;
                mx = fmaxf(mx, sv[u]);
            }
            #pragma unroll
            for (int off = 1; off < 16; off <<= 1)
                mx = fmaxf(mx, __shfl_xor(mx, off, 64));
            float lsum = 0.f;
            #pragma unroll
            for (int u = 0; u < 3; u++) {
                float pv = (sv[u] > -1.0e38f) ? __expf(sv[u] - mx) : 0.f;
                p[mt][u][r] = pv;
                lsum += pv;
            }
            #pragma unroll
            for (int off = 1; off < 16; off <<= 1)
                lsum += __shfl_xor(lsum, off, 64);
            inv[mt][r] = 1.0f / lsum;
        }
    }

    // P -> per-wave scratch (f16), C-layout writes; zero out-of-band tiles
    _Float16 (*myPs)[VSTR] = Ps[h];
    #pragma unroll
    for (int mt = 0; mt < 2; mt++) {
        int zjt = (mt == 0) ? 3 : 0;
        #pragma unroll
        for (int r = 0; r < 4; r++) {
            int row = mt * 16 + quad * 4 + r;
            #pragma unroll
            for (int u = 0; u < 3; u++)
                myPs[row][(u + mt) * 16 + l16] = (_Float16)p[mt][u][r];
            myPs[row][zjt * 16 + l16] = (_Float16)0.f;
        }
    }
    // same-wave producer/consumer: compiler inserts lgkmcnt wait

    half8 pf[2][2], vf[2][2];
    #pragma unroll
    for (int mt = 0; mt < 2; mt++)
        #pragma unroll
        for (int ks = 0; ks < 2; ks++)
            pf[mt][ks] = *(const half8*)&myPs[mt * 16 + l16][ks * 32 + quad * 8];
    #pragma unroll
    for (int dt = 0; dt < 2; dt++)
        #pragma unroll
        for (int ks = 0; ks < 2; ks++)
            vf[dt][ks] = *(const half8*)&Vt[cb + dt * 16 + l16][ks * 32 + quad * 8];

    floatx4 O[2][2];
    #pragma unroll
    for (int mt = 0; mt < 2; mt++)
        #pragma unroll
        for (int dt = 0; dt < 2; dt++) {
            O[mt][dt] = (floatx4)0.f;
            #pragma unroll
            for (int ks = 0; ks < 2; ks++)
                O[mt][dt] = __builtin_amdgcn_mfma_f32_16x16x32_f16(
                    pf[mt][ks], vf[dt][ks], O[mt][dt], 0, 0, 0);
        }

    // Store: O row n = mt*16+quad*4+r, col e = cb+dt*16+l16; scale by 1/l
    const size_t obase = ((size_t)b * 4096 + n0) * 256;
    #pragma unroll
    for (int mt = 0; mt < 2; mt++)
        #pragma unroll
        for (int dt = 0; dt < 2; dt++)
            #pragma unroll
            for (int r = 0; r < 4; r++) {
                int n = mt * 16 + quad * 4 + r;
                out[obase + (size_t)n * 256 + cb + dt * 16 + l16] =
                    O[mt][dt][r] * inv[mt][r];
            }
}

extern "C" void kernel_launch(void* const* d_in, const int* in_sizes, int n_in,
                              void* d_out, int out_size, void* d_ws, size_t ws_size,
                              hipStream_t stream) {
    (void)in_sizes; (void)n_in; (void)out_size; (void)d_ws; (void)ws_size;
    const float* q    = (const float*)d_in[0];
    const float* k    = (const float*)d_in[1];
    const float* v    = (const float*)d_in[2];
    const float* W    = (const float*)d_in[3];
    const float* bias = (const float*)d_in[4];
    float* outp = (float*)d_out;

    hipLaunchKernelGGL(fused_kernel, dim3(128, 2), dim3(512), 0, stream,
                       q, k, v, W, bias, outp);
}